// Round 15
// baseline (89.242 us; speedup 1.0000x reference)
//
#include <hip/hip_runtime.h>
#include <math.h>

#define DIM 256
#define RPW 8

// ---------------------------------------------------------------------------
// K0 setup (4 blocks, one per output qubit q): builds M[q] = T[q] reshaped as
// 16x16 over (j=p0*4+p1, k=p2*4+p3) in d_ws. Validated math (rounds 2-14).
// z_q(row) = sum_{j,k} u_j M[q][j][k] v_k,  u = a0(x)a1, v = a2(x)a3,
// a_i = (1, Ax_i, Ay_i, Az_i) Bloch components; depolarize folded as
// s^(1+nnz), s = 1-4*0.05/3.  Qubit q <-> index bit (3-q).
// ---------------------------------------------------------------------------
__global__ void qc_setup_kernel(const float* __restrict__ qw, float* __restrict__ T)
{
  __shared__ float Vr[16][16], Vi[16][16];
  __shared__ float Or[16][16], Oi[16][16];
  const int tid = threadIdx.x;
  const int r = tid >> 4, c = tid & 15;

  Vr[r][c] = (r == c) ? 1.0f : 0.0f;
  Vi[r][c] = 0.0f;
  __syncthreads();

  #pragma unroll 1
  for (int i = 0; i < 4; ++i) {
    const int cm = 8 >> i;             // control mask (qubit i)
    const int tm = 8 >> ((i + 1) & 3); // target mask (qubit (i+1)%4)
    // CNOT(control=i, target=(i+1)%4): row permutation
    {
      const int k = (r & cm) ? (r ^ tm) : r;
      const float nr = Vr[k][c], ni = Vi[k][c];
      __syncthreads();
      Vr[r][c] = nr; Vi[r][c] = ni;
      __syncthreads();
    }
    const float w  = qw[4 + i];        // qweights[1][i]
    const float ch = cosf(0.5f * w), sh = sinf(0.5f * w);
    // RY(w) on qubit i
    {
      const int m = 8 >> i;
      const int r0 = r & ~m, r1 = r | m;
      float u0, u1;
      if (r & m) { u0 = sh; u1 = ch; } else { u0 = ch; u1 = -sh; }
      const float nr = u0 * Vr[r0][c] + u1 * Vr[r1][c];
      const float ni = u0 * Vi[r0][c] + u1 * Vi[r1][c];
      __syncthreads();
      Vr[r][c] = nr; Vi[r][c] = ni;
      __syncthreads();
    }
    // RZ(w) on qubit i (diagonal)
    {
      const int m = 8 >> i;
      const float pr = ch;
      const float pi = (r & m) ? sh : -sh;
      const float vr = Vr[r][c], vi = Vi[r][c];
      Vr[r][c] = pr * vr - pi * vi;
      Vi[r][c] = pr * vi + pi * vr;
      __syncthreads();
    }
  }

  const int q  = blockIdx.x;           // one q per block
  const int zm = 8 >> q;
  // O[r][c] = sum_k conj(V[k][r]) * sign_q(k) * V[k][c]
  float orr = 0.0f, oii = 0.0f;
  for (int k = 0; k < 16; ++k) {
    const float sgn = (k & zm) ? -1.0f : 1.0f;
    const float ar = Vr[k][r], ai = -Vi[k][r];
    const float br = Vr[k][c], bi = Vi[k][c];
    orr += sgn * (ar * br - ai * bi);
    oii += sgn * (ar * bi + ai * br);
  }
  __syncthreads();
  Or[r][c] = orr; Oi[r][c] = oii;
  __syncthreads();

  // thread tid <-> Pauli string p; Tr(P O) = sum_n P[n][m(n)] * O[m(n)][n]
  const float sdep = 1.0f - 4.0f * 0.05f / 3.0f;
  const int p0 = tid >> 6, p1 = (tid >> 4) & 3, p2 = (tid >> 2) & 3, p3 = tid & 3;
  float tr = 0.0f;
  for (int n = 0; n < 16; ++n) {
    int m = n;
    float fr = 1.0f, fi = 0.0f;
    #pragma unroll
    for (int i2 = 0; i2 < 4; ++i2) {
      const int a   = (n >> (3 - i2)) & 1;
      const int pi_ = (i2 == 0) ? p0 : (i2 == 1) ? p1 : (i2 == 2) ? p2 : p3;
      if (pi_ == 1) {                    // X
        m ^= (8 >> i2);
      } else if (pi_ == 2) {             // Y
        m ^= (8 >> i2);
        const float s2  = a ? 1.0f : -1.0f;
        const float nfr = -fi * s2, nfi = fr * s2;
        fr = nfr; fi = nfi;
      } else if (pi_ == 3) {             // Z
        if (a) { fr = -fr; fi = -fi; }
      }
    }
    tr += fr * Or[m][n] - fi * Oi[m][n];
  }
  const int nnz = (p0 != 0) + (p1 != 0) + (p2 != 0) + (p3 != 0);
  float scale = 1.0f / 16.0f;
  for (int e = 0; e <= nnz; ++e) scale *= sdep;
  // p = p0*64+p1*16+p2*4+p3 = (p0*4+p1)*16 + (p2*4+p3): already M[q][j][k].
  T[q * 256 + tid] = tr * scale;
}

// ---------------------------------------------------------------------------
// Main kernel (round-15): BARRIER-FREE wave-self-contained, RPW=8.
// Round-14 falsified the residency-cap theory: spill-free VGPR=64 + cap 8
// still gave 31% occupancy -> the 512-thr barrier structure itself convoys.
// This kernel has no __syncthreads and no __shared__:
//   A (proven r10): xr[8] reg-tile, per-row 6-step butterfly, lane i keeps.
//   B (new): broadcast acc to 8-lane row group (rrow=lane>>3); all lanes do
//      the cheap middle (tanh/LN/Bloch, 8x redundant); the 1088-FMA
//      contraction is SPLIT across the row's 8 lanes (lane=(q,jhalf), M via
//      per-lane vector loads, L1-resident 4KB) + one shfl_xor(1) combine.
//   C (proven r10): readlane z broadcast, epilogue from xr regs, zero loads.
// 8192 independent waves (2048 x 256thr); waves_per_eu(4,8) = 128-reg budget.
// ---------------------------------------------------------------------------
__global__ __launch_bounds__(256)
__attribute__((amdgpu_waves_per_eu(4, 8)))
void qlayer_main_kernel(
    const float* __restrict__ x,
    const float* __restrict__ Win,
    const float* __restrict__ b_in,
    const float* __restrict__ gamma,
    const float* __restrict__ beta,
    const float* __restrict__ qw,
    const float* __restrict__ Wout,
    const float* __restrict__ b_out,
    const float* __restrict__ M,
    float* __restrict__ out,
    int B)
{
  const int tid  = threadIdx.x;
  const int lane = tid & 63;
  const int wg   = blockIdx.x * (blockDim.x >> 6) + (tid >> 6);
  const size_t row0 = (size_t)wg * RPW;

  // ================= Phase A: reg-tile GEMV + per-row butterfly ============
  float4 winf[4];
  #pragma unroll
  for (int q = 0; q < 4; ++q)
    winf[q] = *reinterpret_cast<const float4*>(&Win[q * 256 + lane * 4]);

  float4 xr[RPW];
  #pragma unroll
  for (int i = 0; i < RPW; ++i)
    xr[i] = *reinterpret_cast<const float4*>(&x[(row0 + i) * DIM + lane * 4]);

  float am[4] = {0.0f, 0.0f, 0.0f, 0.0f};   // lane i<8 keeps row i's acc
  #pragma unroll
  for (int i = 0; i < RPW; ++i) {
    const float4 xv = xr[i];
    float a[4];
    #pragma unroll
    for (int q = 0; q < 4; ++q)
      a[q] = xv.x * winf[q].x + xv.y * winf[q].y + xv.z * winf[q].z + xv.w * winf[q].w;
    #pragma unroll
    for (int off = 1; off < 64; off <<= 1) {
      #pragma unroll
      for (int q = 0; q < 4; ++q) a[q] += __shfl_xor(a[q], off, 64);
    }
    if (lane == i) { am[0] = a[0]; am[1] = a[1]; am[2] = a[2]; am[3] = a[3]; }
  }

  // ================= Phase B: intra-wave parallel middle ===================
  const int rrow = lane >> 3;          // my row within the wave's 8
  const int sub  = lane & 7;           // my slot within the row group
  const int q_   = sub >> 1;           // my output qubit
  const int jh   = sub & 1;            // my j-half (j = jh*8 + jj)

  float aq[4];
  #pragma unroll
  for (int q = 0; q < 4; ++q)
    aq[q] = __shfl(am[q], rrow, 64);   // broadcast from holder lane rrow

  float xp[4];
  #pragma unroll
  for (int q = 0; q < 4; ++q) {
    const float e = __expf(2.0f * (aq[q] + b_in[q]));
    xp[q] = 1.0f - __fdividef(2.0f, e + 1.0f);   // tanh, inf-safe
  }
  const float mu = 0.25f * (xp[0] + xp[1] + xp[2] + xp[3]);
  const float d0 = xp[0] - mu, d1 = xp[1] - mu, d2 = xp[2] - mu, d3 = xp[3] - mu;
  const float var = 0.25f * (d0 * d0 + d1 * d1 + d2 * d2 + d3 * d3);
  const float inv = rsqrtf(var + 1e-5f);

  float A0[4], A1[4], A2[4], A3[4];    // a_i = (1, Ax, Ay, Az)
  #pragma unroll
  for (int i = 0; i < 4; ++i) {
    const float w0 = qw[i], w1 = qw[4 + i];
    const float cwa = cosf(w0), swa = sinf(w0);
    const float cwb = cosf(w1), swb = sinf(w1);
    const float ang = ((i == 0 ? d0 : i == 1 ? d1 : i == 2 ? d2 : d3) * inv) * gamma[i] + beta[i];
    float sn, cs;
    __sincosf(ang, &sn, &cs);
    const float ax = sn * sn;                     // RX(t) then RZ(t)
    const float ay = -sn * cs;
    const float az = cs;
    const float ay2 = ay * cwa - az * swa;        // RX(w0)
    const float az2 = ay * swa + az * cwa;
    const float Axv = ax * cwb - ay2 * swb;       // RZ(w1)
    const float Ayv = ax * swb + ay2 * cwb;
    float* dst = (i == 0) ? A0 : (i == 1) ? A1 : (i == 2) ? A2 : A3;
    dst[0] = 1.0f; dst[1] = Axv; dst[2] = Ayv; dst[3] = az2;
  }

  float v[16];
  #pragma unroll
  for (int a = 0; a < 4; ++a)
    #pragma unroll
    for (int b = 0; b < 4; ++b)
      v[a * 4 + b] = A2[a] * A3[b];

  // contraction slice: zp = sum_{jj<8} u_{jh*8+jj} * (M[q_][jh*8+jj] . v)
  const float* Mlane = M + q_ * 256 + jh * 128;
  float zp = 0.0f;
  #pragma unroll
  for (int jj = 0; jj < 8; ++jj) {
    const float4 m0 = *reinterpret_cast<const float4*>(&Mlane[jj * 16 + 0]);
    const float4 m1 = *reinterpret_cast<const float4*>(&Mlane[jj * 16 + 4]);
    const float4 m2 = *reinterpret_cast<const float4*>(&Mlane[jj * 16 + 8]);
    const float4 m3 = *reinterpret_cast<const float4*>(&Mlane[jj * 16 + 12]);
    const float w =
        m0.x * v[0]  + m0.y * v[1]  + m0.z * v[2]  + m0.w * v[3] +
        m1.x * v[4]  + m1.y * v[5]  + m1.z * v[6]  + m1.w * v[7] +
        m2.x * v[8]  + m2.y * v[9]  + m2.z * v[10] + m2.w * v[11] +
        m3.x * v[12] + m3.y * v[13] + m3.z * v[14] + m3.w * v[15];
    const float a0v = jh ? A0[2 + (jj >> 2)] : A0[(jj >> 2)];  // static idx both arms
    zp += a0v * A1[jj & 3] * w;
  }
  const float zfull = zp + __shfl_xor(zp, 1, 64);
  // row i's z_q now lives on lanes i*8 + q*2 (and +1)

  // ================= Phase C: epilogue from regs + readlane z ==============
  float4 woutf[4];
  #pragma unroll
  for (int j = 0; j < 4; ++j)
    woutf[j] = *reinterpret_cast<const float4*>(&Wout[(lane * 4 + j) * 4]);
  const float4 boutf = *reinterpret_cast<const float4*>(&b_out[lane * 4]);

  #pragma unroll
  for (int i = 0; i < RPW; ++i) {
    const float zq0 = __shfl(zfull, i * 8 + 0, 64);   // const lane -> readlane
    const float zq1 = __shfl(zfull, i * 8 + 2, 64);
    const float zq2 = __shfl(zfull, i * 8 + 4, 64);
    const float zq3 = __shfl(zfull, i * 8 + 6, 64);
    const float4 xv = xr[i];
    float4 o;
    o.x = xv.x + boutf.x + zq0 * woutf[0].x + zq1 * woutf[0].y + zq2 * woutf[0].z + zq3 * woutf[0].w;
    o.y = xv.y + boutf.y + zq0 * woutf[1].x + zq1 * woutf[1].y + zq2 * woutf[1].z + zq3 * woutf[1].w;
    o.z = xv.z + boutf.z + zq0 * woutf[2].x + zq1 * woutf[2].y + zq2 * woutf[2].z + zq3 * woutf[2].w;
    o.w = xv.w + boutf.w + zq0 * woutf[3].x + zq1 * woutf[3].y + zq2 * woutf[3].z + zq3 * woutf[3].w;
    *reinterpret_cast<float4*>(&out[(row0 + i) * DIM + lane * 4]) = o;
  }
}

extern "C" void kernel_launch(void* const* d_in, const int* in_sizes, int n_in,
                              void* d_out, int out_size, void* d_ws, size_t ws_size,
                              hipStream_t stream)
{
  const float* x     = (const float*)d_in[0];
  const float* Win   = (const float*)d_in[1];
  const float* b_in  = (const float*)d_in[2];
  const float* gamma = (const float*)d_in[3];
  const float* beta  = (const float*)d_in[4];
  const float* qw    = (const float*)d_in[5];
  const float* Wout  = (const float*)d_in[6];
  const float* b_out = (const float*)d_in[7];
  float* out = (float*)d_out;
  float* T   = (float*)d_ws;            // M[4][16][16] = 4 KB
  const int B = in_sizes[0] / DIM;

  hipLaunchKernelGGL(qc_setup_kernel, dim3(4), dim3(256), 0, stream, qw, T);

  const int nwaves  = (B + RPW - 1) / RPW;          // 8192 for B=65536
  const int nblocks = (nwaves + 3) / 4;             // 4 waves/block -> 2048
  hipLaunchKernelGGL(qlayer_main_kernel, dim3(nblocks), dim3(256), 0, stream,
                     x, Win, b_in, gamma, beta, qw, Wout, b_out, T, out, B);
}

// Round 16
// 63.421 us; speedup vs baseline: 1.4071x; 1.4071x over previous
//
#include <hip/hip_runtime.h>
#include <math.h>

#define DIM 256
#define RPW 4

// ---------------------------------------------------------------------------
// K0 setup (4 blocks, one per output qubit q): builds M[q] = T[q] reshaped as
// 16x16 over (j=p0*4+p1, k=p2*4+p3) in d_ws. Validated math (rounds 2-15).
// z_q(row) = sum_{j,k} u_j M[q][j][k] v_k,  u = a0(x)a1, v = a2(x)a3,
// a_i = (1, Ax_i, Ay_i, Az_i) Bloch components; depolarize folded as
// s^(1+nnz), s = 1-4*0.05/3.  Qubit q <-> index bit (3-q).
// ---------------------------------------------------------------------------
__global__ void qc_setup_kernel(const float* __restrict__ qw, float* __restrict__ T)
{
  __shared__ float Vr[16][16], Vi[16][16];
  __shared__ float Or[16][16], Oi[16][16];
  const int tid = threadIdx.x;
  const int r = tid >> 4, c = tid & 15;

  Vr[r][c] = (r == c) ? 1.0f : 0.0f;
  Vi[r][c] = 0.0f;
  __syncthreads();

  #pragma unroll 1
  for (int i = 0; i < 4; ++i) {
    const int cm = 8 >> i;             // control mask (qubit i)
    const int tm = 8 >> ((i + 1) & 3); // target mask (qubit (i+1)%4)
    // CNOT(control=i, target=(i+1)%4): row permutation
    {
      const int k = (r & cm) ? (r ^ tm) : r;
      const float nr = Vr[k][c], ni = Vi[k][c];
      __syncthreads();
      Vr[r][c] = nr; Vi[r][c] = ni;
      __syncthreads();
    }
    const float w  = qw[4 + i];        // qweights[1][i]
    const float ch = cosf(0.5f * w), sh = sinf(0.5f * w);
    // RY(w) on qubit i
    {
      const int m = 8 >> i;
      const int r0 = r & ~m, r1 = r | m;
      float u0, u1;
      if (r & m) { u0 = sh; u1 = ch; } else { u0 = ch; u1 = -sh; }
      const float nr = u0 * Vr[r0][c] + u1 * Vr[r1][c];
      const float ni = u0 * Vi[r0][c] + u1 * Vi[r1][c];
      __syncthreads();
      Vr[r][c] = nr; Vi[r][c] = ni;
      __syncthreads();
    }
    // RZ(w) on qubit i (diagonal)
    {
      const int m = 8 >> i;
      const float pr = ch;
      const float pi = (r & m) ? sh : -sh;
      const float vr = Vr[r][c], vi = Vi[r][c];
      Vr[r][c] = pr * vr - pi * vi;
      Vi[r][c] = pr * vi + pi * vr;
      __syncthreads();
    }
  }

  const int q  = blockIdx.x;           // one q per block
  const int zm = 8 >> q;
  // O[r][c] = sum_k conj(V[k][r]) * sign_q(k) * V[k][c]
  float orr = 0.0f, oii = 0.0f;
  for (int k = 0; k < 16; ++k) {
    const float sgn = (k & zm) ? -1.0f : 1.0f;
    const float ar = Vr[k][r], ai = -Vi[k][r];
    const float br = Vr[k][c], bi = Vi[k][c];
    orr += sgn * (ar * br - ai * bi);
    oii += sgn * (ar * bi + ai * br);
  }
  __syncthreads();
  Or[r][c] = orr; Oi[r][c] = oii;
  __syncthreads();

  // thread tid <-> Pauli string p; Tr(P O) = sum_n P[n][m(n)] * O[m(n)][n]
  const float sdep = 1.0f - 4.0f * 0.05f / 3.0f;
  const int p0 = tid >> 6, p1 = (tid >> 4) & 3, p2 = (tid >> 2) & 3, p3 = tid & 3;
  float tr = 0.0f;
  for (int n = 0; n < 16; ++n) {
    int m = n;
    float fr = 1.0f, fi = 0.0f;
    #pragma unroll
    for (int i2 = 0; i2 < 4; ++i2) {
      const int a   = (n >> (3 - i2)) & 1;
      const int pi_ = (i2 == 0) ? p0 : (i2 == 1) ? p1 : (i2 == 2) ? p2 : p3;
      if (pi_ == 1) {                    // X
        m ^= (8 >> i2);
      } else if (pi_ == 2) {             // Y
        m ^= (8 >> i2);
        const float s2  = a ? 1.0f : -1.0f;
        const float nfr = -fi * s2, nfi = fr * s2;
        fr = nfr; fi = nfi;
      } else if (pi_ == 3) {             // Z
        if (a) { fr = -fr; fi = -fi; }
      }
    }
    tr += fr * Or[m][n] - fi * Oi[m][n];
  }
  const int nnz = (p0 != 0) + (p1 != 0) + (p2 != 0) + (p3 != 0);
  float scale = 1.0f / 16.0f;
  for (int e = 0; e <= nnz; ++e) scale *= sdep;
  // p = p0*64+p1*16+p2*4+p3 = (p0*4+p1)*16 + (p2*4+p3): already M[q][j][k].
  T[q * 256 + tid] = tr * scale;
}

// ---------------------------------------------------------------------------
// Main kernel (round-16): barrier-free, LDS-free, sized to fit 64 VGPRs.
// Lesson r15: the allocator targets the waves_per_eu MAX (budget 512/max) and
// spills to scratch+LDS to get there. Fix: make the live set genuinely fit 64
// (RPW=4 -> xr[4]=16 regs; 16-lane B split) and drop all attributes.
//   A: xr[4] reg-tile; per row 6-step butterfly (result broadcast to all 64
//      lanes); lanes with rrow==i capture (cndmask, no extra shuffles).
//   B: row group = 16 lanes (rrow=lane>>4); all lanes do the cheap middle for
//      their row; contraction split lane=(q_, jq): 4 jj x 16 FMA with
//      u_j = A0[jq]*A1[jj] (static idx), M via float4 VMEM (4KB, L1-resident);
//      combine with shfl_xor(1) + shfl_xor(2).
//   C: readlane z broadcast; epilogue from xr regs; zero loads.
// 16384 independent waves (4096 x 256 thr) -> 2x r14's TLP, 8 waves/SIMD
// reachable at VGPR<=64.
// ---------------------------------------------------------------------------
__global__ __launch_bounds__(256) void qlayer_main_kernel(
    const float* __restrict__ x,
    const float* __restrict__ Win,
    const float* __restrict__ b_in,
    const float* __restrict__ gamma,
    const float* __restrict__ beta,
    const float* __restrict__ qw,
    const float* __restrict__ Wout,
    const float* __restrict__ b_out,
    const float* __restrict__ M,
    float* __restrict__ out,
    int B)
{
  const int tid  = threadIdx.x;
  const int lane = tid & 63;
  const int wg   = blockIdx.x * (blockDim.x >> 6) + (tid >> 6);
  const size_t row0 = (size_t)wg * RPW;

  const int rrow = lane >> 4;          // my row within the wave's 4
  const int sub  = lane & 15;          // slot within the 16-lane row group
  const int q_   = sub >> 2;           // my output qubit
  const int jq   = sub & 3;            // my j-quarter (j = jq*4 + jj)

  // ================= Phase A: reg-tile GEMV + per-row butterfly ============
  float4 winf[4];
  #pragma unroll
  for (int q = 0; q < 4; ++q)
    winf[q] = *reinterpret_cast<const float4*>(&Win[q * 256 + lane * 4]);

  float4 xr[RPW];
  #pragma unroll
  for (int i = 0; i < RPW; ++i)
    xr[i] = *reinterpret_cast<const float4*>(&x[(row0 + i) * DIM + lane * 4]);

  float aq[4] = {0.0f, 0.0f, 0.0f, 0.0f};   // my row's acc (captured below)
  #pragma unroll
  for (int i = 0; i < RPW; ++i) {
    const float4 xv = xr[i];
    float a[4];
    #pragma unroll
    for (int q = 0; q < 4; ++q)
      a[q] = xv.x * winf[q].x + xv.y * winf[q].y + xv.z * winf[q].z + xv.w * winf[q].w;
    #pragma unroll
    for (int off = 1; off < 64; off <<= 1) {
      #pragma unroll
      for (int q = 0; q < 4; ++q) a[q] += __shfl_xor(a[q], off, 64);
    }
    // butterfly leaves the full sum on all 64 lanes; my row group captures
    #pragma unroll
    for (int q = 0; q < 4; ++q) aq[q] = (rrow == i) ? a[q] : aq[q];
  }

  // ================= Phase B: middle + 16-way-split contraction ============
  float xp[4];
  #pragma unroll
  for (int q = 0; q < 4; ++q) {
    const float e = __expf(2.0f * (aq[q] + b_in[q]));
    xp[q] = 1.0f - __fdividef(2.0f, e + 1.0f);   // tanh, inf-safe
  }
  const float mu = 0.25f * (xp[0] + xp[1] + xp[2] + xp[3]);
  const float d0 = xp[0] - mu, d1 = xp[1] - mu, d2 = xp[2] - mu, d3 = xp[3] - mu;
  const float var = 0.25f * (d0 * d0 + d1 * d1 + d2 * d2 + d3 * d3);
  const float inv = rsqrtf(var + 1e-5f);

  float A0[4], A1[4], A2[4], A3[4];    // a_i = (1, Ax, Ay, Az)
  #pragma unroll
  for (int i = 0; i < 4; ++i) {
    const float w0 = qw[i], w1 = qw[4 + i];
    const float cwa = cosf(w0), swa = sinf(w0);
    const float cwb = cosf(w1), swb = sinf(w1);
    const float ang = ((i == 0 ? d0 : i == 1 ? d1 : i == 2 ? d2 : d3) * inv) * gamma[i] + beta[i];
    float sn, cs;
    __sincosf(ang, &sn, &cs);
    const float ax = sn * sn;                     // RX(t) then RZ(t)
    const float ay = -sn * cs;
    const float az = cs;
    const float ay2 = ay * cwa - az * swa;        // RX(w0)
    const float az2 = ay * swa + az * cwa;
    const float Axv = ax * cwb - ay2 * swb;       // RZ(w1)
    const float Ayv = ax * swb + ay2 * cwb;
    float* dst = (i == 0) ? A0 : (i == 1) ? A1 : (i == 2) ? A2 : A3;
    dst[0] = 1.0f; dst[1] = Axv; dst[2] = Ayv; dst[3] = az2;
  }

  float v[16];
  #pragma unroll
  for (int a = 0; a < 4; ++a)
    #pragma unroll
    for (int b = 0; b < 4; ++b)
      v[a * 4 + b] = A2[a] * A3[b];

  // my contraction slice: j = jq*4 + jj  ->  u_j = A0[jq] * A1[jj]
  const float* Mrow = M + q_ * 256 + jq * 64;
  float zp = 0.0f;
  #pragma unroll
  for (int jj = 0; jj < 4; ++jj) {
    const float4 m0 = *reinterpret_cast<const float4*>(&Mrow[jj * 16 + 0]);
    const float4 m1 = *reinterpret_cast<const float4*>(&Mrow[jj * 16 + 4]);
    const float4 m2 = *reinterpret_cast<const float4*>(&Mrow[jj * 16 + 8]);
    const float4 m3 = *reinterpret_cast<const float4*>(&Mrow[jj * 16 + 12]);
    const float w =
        m0.x * v[0]  + m0.y * v[1]  + m0.z * v[2]  + m0.w * v[3] +
        m1.x * v[4]  + m1.y * v[5]  + m1.z * v[6]  + m1.w * v[7] +
        m2.x * v[8]  + m2.y * v[9]  + m2.z * v[10] + m2.w * v[11] +
        m3.x * v[12] + m3.y * v[13] + m3.z * v[14] + m3.w * v[15];
    zp += A0[jq] * A1[jj] * w;
  }
  float zs = zp + __shfl_xor(zp, 1, 64);
  zs += __shfl_xor(zs, 2, 64);
  // row i's z_q now lives on lanes i*16 + q*4 + {0..3}

  // ================= Phase C: epilogue from regs + readlane z ==============
  float4 woutf[4];
  #pragma unroll
  for (int j = 0; j < 4; ++j)
    woutf[j] = *reinterpret_cast<const float4*>(&Wout[(lane * 4 + j) * 4]);
  const float4 boutf = *reinterpret_cast<const float4*>(&b_out[lane * 4]);

  #pragma unroll
  for (int i = 0; i < RPW; ++i) {
    const float zq0 = __shfl(zs, i * 16 + 0,  64);   // const lane -> readlane
    const float zq1 = __shfl(zs, i * 16 + 4,  64);
    const float zq2 = __shfl(zs, i * 16 + 8,  64);
    const float zq3 = __shfl(zs, i * 16 + 12, 64);
    const float4 xv = xr[i];
    float4 o;
    o.x = xv.x + boutf.x + zq0 * woutf[0].x + zq1 * woutf[0].y + zq2 * woutf[0].z + zq3 * woutf[0].w;
    o.y = xv.y + boutf.y + zq0 * woutf[1].x + zq1 * woutf[1].y + zq2 * woutf[1].z + zq3 * woutf[1].w;
    o.z = xv.z + boutf.z + zq0 * woutf[2].x + zq1 * woutf[2].y + zq2 * woutf[2].z + zq3 * woutf[2].w;
    o.w = xv.w + boutf.w + zq0 * woutf[3].x + zq1 * woutf[3].y + zq2 * woutf[3].z + zq3 * woutf[3].w;
    *reinterpret_cast<float4*>(&out[(row0 + i) * DIM + lane * 4]) = o;
  }
}

extern "C" void kernel_launch(void* const* d_in, const int* in_sizes, int n_in,
                              void* d_out, int out_size, void* d_ws, size_t ws_size,
                              hipStream_t stream)
{
  const float* x     = (const float*)d_in[0];
  const float* Win   = (const float*)d_in[1];
  const float* b_in  = (const float*)d_in[2];
  const float* gamma = (const float*)d_in[3];
  const float* beta  = (const float*)d_in[4];
  const float* qw    = (const float*)d_in[5];
  const float* Wout  = (const float*)d_in[6];
  const float* b_out = (const float*)d_in[7];
  float* out = (float*)d_out;
  float* T   = (float*)d_ws;            // M[4][16][16] = 4 KB
  const int B = in_sizes[0] / DIM;

  hipLaunchKernelGGL(qc_setup_kernel, dim3(4), dim3(256), 0, stream, qw, T);

  const int nwaves  = (B + RPW - 1) / RPW;          // 16384 for B=65536
  const int nblocks = (nwaves + 3) / 4;             // 4 waves/block -> 4096
  hipLaunchKernelGGL(qlayer_main_kernel, dim3(nblocks), dim3(256), 0, stream,
                     x, Win, b_in, gamma, beta, qw, Wout, b_out, T, out, B);
}